// Round 11
// baseline (196.702 us; speedup 1.0000x reference)
//
#include <hip/hip_runtime.h>
#include <hip/hip_bf16.h>
#include <math.h>

#define N_PTS 16384
#define DIM   512
#define BMR   128               // tile rows
#define BNC   256               // tile cols
#define BK    64                // i8: 64-byte LDS rows
#define NRB   (N_PTS / BMR)     // 128 row-blocks
#define NCB   (N_PTS / BNC)     // 64 col-blocks
#define NTILE 4160              // sum_{g=0}^{63} 2*(64-g)
#define QSCALE 23.0f
#define BIAS   (1 << 23)        // |dot| <= 512*127^2 = 8258048 < 2^23

typedef int i32x4  __attribute__((ext_vector_type(4)));
typedef int i32x16 __attribute__((ext_vector_type(16)));
typedef unsigned long long u64;

#define VMC3    asm volatile("s_waitcnt vmcnt(3)" ::: "memory")
#define VMC0    asm volatile("s_waitcnt vmcnt(0)" ::: "memory")
#define BARRIER __builtin_amdgcn_s_barrier()

__device__ __forceinline__ u64 pmax64(u64 a, u64 b) { return a > b ? a : b; }
__device__ __forceinline__ unsigned umax32(unsigned a, unsigned b) { return a > b ? a : b; }
// DPP-based max step (VALU, off the LDS crossbar). CTRL must be literal.
template <int CTRL>
__device__ __forceinline__ unsigned dppmax(unsigned p) {
    int t = __builtin_amdgcn_update_dpp(0, (int)p, CTRL, 0xF, 0xF, true);
    return umax32(p, (unsigned)t);
}
__device__ __forceinline__ void gll(const char* g, char* l) {
    __builtin_amdgcn_global_load_lds(
        (const __attribute__((address_space(1))) void*)g,
        (__attribute__((address_space(3))) void*)l, 16, 0, 0);
}

// =====================================================================
// Kernel 1: fp32 -> int8 quantize
// =====================================================================
__global__ void k_quant(const float* __restrict__ x, char* __restrict__ xq) {
    int t = blockIdx.x * blockDim.x + threadIdx.x;
    size_t e = (size_t)t * 8;
    float4 f0 = *(const float4*)(x + e);
    float4 f1 = *(const float4*)(x + e + 4);
    auto q8 = [](float v) -> int {
        return (int)rintf(fminf(fmaxf(v * QSCALE, -127.0f), 127.0f));
    };
    int lo = (q8(f0.x) & 255) | ((q8(f0.y) & 255) << 8)
           | ((q8(f0.z) & 255) << 16) | ((q8(f0.w) & 255) << 24);
    int hi = (q8(f1.x) & 255) | ((q8(f1.y) & 255) << 8)
           | ((q8(f1.z) & 255) << 16) | ((q8(f1.w) & 255) << 24);
    int2 o; o.x = lo; o.y = hi;
    *(int2*)(xq + e) = o;
}

// =====================================================================
// Kernel 2 (byte-identical to R10-verified): 128x256 tiles, 8 waves 2x4,
// wave tile 64x64, i8 MFMA, BK=64, triple-buffer counted vmcnt(3),
// XOR-swizzled LDS, swizzle-free DPP epilogue -> PT slots.
// =====================================================================
__global__ __launch_bounds__(512, 4)
void k_gemm_argmax(const char* __restrict__ xq, unsigned* __restrict__ PT) {
    __shared__ __align__(16) char As0[BMR * BK], As1[BMR * BK], As2[BMR * BK];   // 8 KB ea
    __shared__ __align__(16) char Bs0[BNC * BK], Bs1[BNC * BK], Bs2[BNC * BK];   // 16 KB ea

    // T1: XCD swizzle (4160 % 8 == 0)
    int t0i = (int)blockIdx.x;
    int t = (t0i & 7) * (NTILE / 8) + (t0i >> 3);

    // decode t -> (br, bc): groups g = br>>1, S(g) = g*(129-g)
    int g = (int)((129.0f - sqrtf(16641.0f - 4.0f * (float)t)) * 0.5f);
    while (g * (129 - g) > t) --g;
    while ((g + 1) * (128 - g) <= t) ++g;
    int u = t - g * (129 - g);
    int bc = g + (u >> 1);
    int br = 2 * g + (u & 1);

    const int tid  = (int)threadIdx.x;
    const int lane = tid & 63;
    const int wave = tid >> 6;       // 0..7
    const int wr   = wave >> 2;      // 0/1 -> 64-row band
    const int wc   = wave & 3;       // 0..3 -> 64-col band
    const int l31  = lane & 31;
    const int h    = lane >> 5;

    const int arow0 = br * BMR;
    const int bcol0 = bc * BNC;

    // staging: A = 512 chunks (1/thread), B = 1024 chunks (2/thread)
    // LDS linear; SOURCE inverse-swizzled: col16 = (tid&3) ^ ((row>>1)&3)
    const int srow   = tid >> 2;                        // 0..127
    const int scol16 = (tid & 3) ^ ((tid >> 3) & 3);
    const char* gA  = xq + (size_t)(arow0 + srow)       * DIM + scol16 * 16;
    const char* gB0 = xq + (size_t)(bcol0 + srow)       * DIM + scol16 * 16;
    const char* gB1 = xq + (size_t)(bcol0 + 128 + srow) * DIM + scol16 * 16;
    const int cbA  = (tid & ~63) * 16;
    const int cbB0 = cbA;
    const int cbB1 = (512 + (tid & ~63)) * 16;

#define STAGE(Ad, Bd, kt)                                                \
    do {                                                                 \
        int ko = (kt) * BK;                                              \
        gll(gA + ko, (Ad) + cbA);                                        \
        gll(gB0 + ko, (Bd) + cbB0);                                      \
        gll(gB1 + ko, (Bd) + cbB1);                                      \
    } while (0)

    // fragment read byte offsets: row*64 + ((q ^ ((row>>1)&3))<<4), q=s*2+h
    const int rw = (l31 >> 1) & 3;
    const int aoff0 = (wr * 64 + 0  + l31) * 64 + ((h ^ rw) << 4);
    const int aoff1 = (wr * 64 + 32 + l31) * 64 + ((h ^ rw) << 4);
    const int boff0 = (wc * 64 + 0  + l31) * 64 + ((h ^ rw) << 4);
    const int boff1 = (wc * 64 + 32 + l31) * 64 + ((h ^ rw) << 4);

    i32x16 acc[2][2] = {};

#define COMPUTE(As_, Bs_)                                                              \
    do {                                                                               \
        _Pragma("unroll")                                                              \
        for (int s = 0; s < 2; ++s) {                                                  \
            const int xo = s * 32;                                                     \
            i32x4 a0 = *(const i32x4*)((As_) + (aoff0 ^ xo));                          \
            i32x4 a1 = *(const i32x4*)((As_) + (aoff1 ^ xo));                          \
            i32x4 b0 = *(const i32x4*)((Bs_) + (boff0 ^ xo));                          \
            i32x4 b1 = *(const i32x4*)((Bs_) + (boff1 ^ xo));                          \
            acc[0][0] = __builtin_amdgcn_mfma_i32_32x32x32_i8(a0, b0, acc[0][0], 0, 0, 0); \
            acc[0][1] = __builtin_amdgcn_mfma_i32_32x32x32_i8(a0, b1, acc[0][1], 0, 0, 0); \
            acc[1][0] = __builtin_amdgcn_mfma_i32_32x32x32_i8(a1, b0, acc[1][0], 0, 0, 0); \
            acc[1][1] = __builtin_amdgcn_mfma_i32_32x32x32_i8(a1, b1, acc[1][1], 0, 0, 0); \
        }                                                                              \
    } while (0)

    // ---- prologue: stage tiles 0,1; wait tile 0 only ----
    STAGE(As0, Bs0, 0);
    STAGE(As1, Bs1, 1);
    VMC3;
    BARRIER;

    // ---- 8 K-tiles, buffers rotate 0,1,2; vmcnt(3) counted, never 0 mid-loop ----
    STAGE(As2, Bs2, 2); COMPUTE(As0, Bs0); VMC3; BARRIER;
    STAGE(As0, Bs0, 3); COMPUTE(As1, Bs1); VMC3; BARRIER;
    STAGE(As1, Bs1, 4); COMPUTE(As2, Bs2); VMC3; BARRIER;
    STAGE(As2, Bs2, 5); COMPUTE(As0, Bs0); VMC3; BARRIER;
    STAGE(As0, Bs0, 6); COMPUTE(As1, Bs1); VMC3; BARRIER;
    STAGE(As1, Bs1, 7); COMPUTE(As2, Bs2); VMC3; BARRIER;
    COMPUTE(As0, Bs0);  VMC0; BARRIER;          // after this barrier As0/Bs0 quiesced
    COMPUTE(As1, Bs1);                          // t7

    // ---- epilogue (swizzle-free) ----
    // C/D 32x32 layout: col = lane&31, row = (r&3) + 8*(r>>2) + 4*(lane>>5)
    const bool diag = ((br >> 1) == bc);
    const int  poff = (br & 1) * 128;
    unsigned* rbuf = (unsigned*)As0;   // [128][8] row partials (4 KB)
    unsigned* cbuf = (unsigned*)Bs0;   // [256][4] col partials (4 KB)
    const int cl0 = wc * 64 + l31;
    const int s16 = (l31 >> 4) & 1;
    const unsigned Cr0 = ((unsigned)BIAS << 8) | (unsigned)(255 - cl0);
    const unsigned Cr1 = Cr0 - 32;

    auto epi = [&](bool dg) {
#pragma unroll
        for (int m = 0; m < 2; ++m) {
#pragma unroll
            for (int r = 0; r < 16; ++r) {
                int rl = wr * 64 + m * 32 + (r & 3) + 8 * (r >> 2) + 4 * h;
                unsigned q0 = ((unsigned)acc[m][0][r] << 8) + Cr0;
                unsigned q1 = ((unsigned)acc[m][1][r] << 8) + Cr1;
                if (dg && cl0 == rl + poff) q0 = 0;
                if (dg && cl0 + 32 == rl + poff) q1 = 0;
                unsigned p = umax32(q0, q1);
                p = dppmax<0xB1>(p);    // xor1
                p = dppmax<0x4E>(p);    // xor2
                p = dppmax<0x141>(p);   // half_mirror
                p = dppmax<0x140>(p);   // mirror
                if ((l31 & 15) == 0) rbuf[rl * 8 + wc * 2 + s16] = p;
            }
        }
#pragma unroll
        for (int n = 0; n < 2; ++n) {
            int cl = cl0 + n * 32;
            unsigned bst = 0;
#pragma unroll
            for (int m = 0; m < 2; ++m) {
#pragma unroll
                for (int r = 0; r < 16; ++r) {
                    int base = wr * 64 + m * 32 + (r & 3) + 8 * (r >> 2);
                    unsigned q = ((unsigned)acc[m][n][r] << 7)
                               + (((unsigned)BIAS << 7) | (unsigned)(127 - base));
                    if (dg && cl == base + 4 * h + poff) q = 0;
                    bst = umax32(bst, q);
                }
            }
            bst -= (unsigned)(4 * h);
            cbuf[cl * 4 + wr * 2 + h] = bst;
        }
    };
    if (diag) epi(true); else epi(false);

    __syncthreads();
    if (tid < 128) {
        const unsigned* rb = rbuf + tid * 8;
        unsigned w = umax32(umax32(umax32(rb[0], rb[1]), umax32(rb[2], rb[3])),
                            umax32(umax32(rb[4], rb[5]), umax32(rb[6], rb[7])));
        PT[(size_t)bc * N_PTS + arow0 + tid] = w;               // row-view slot bc
    } else if (tid < 384) {
        int c = tid - 128;
        const unsigned* cb = cbuf + c * 4;
        unsigned w = umax32(umax32(cb[0], cb[1]), umax32(cb[2], cb[3]));
        PT[(size_t)(NCB + br) * N_PTS + bcol0 + c] = w;         // col-view slot br
    }
#undef STAGE
#undef COMPUTE
}

// =====================================================================
// Kernel 3 (fused): phase 1 = PT slot scan -> nb (LDS), coalesced,
// uniform slot range per 256-row block (rb8 = r>>8 constant in block);
// phase 2 = per-row fp32 loss: log(||x_r - x_I + 1e-6|| + 1e-8).
// =====================================================================
__global__ __launch_bounds__(256)
void k_nn(const unsigned* __restrict__ PT, const float* __restrict__ x,
          float* __restrict__ rowloss) {
    __shared__ int nbs[256];
    const int r0 = (int)blockIdx.x * 256;
    {
        int r = r0 + (int)threadIdx.x;
        int rb8 = r >> 8;
        u64 bst = 0;
        for (int bc = rb8; bc < NCB; ++bc) {
            unsigned p = PT[(size_t)bc * N_PTS + r];
            unsigned j = bc * 256 + 255 - (p & 255);
            bst = pmax64(bst, ((u64)(p >> 8) << 14) | (16383 - j));
        }
        int brmax = 2 * rb8 + 1;
        for (int br = 0; br <= brmax; ++br) {
            unsigned p = PT[(size_t)(NCB + br) * N_PTS + r];
            unsigned j = br * 128 + 127 - (p & 127);
            bst = pmax64(bst, ((u64)(p >> 7) << 14) | (16383 - j));
        }
        nbs[threadIdx.x] = 16383 - (int)(bst & 16383);
    }
    __syncthreads();
    const int wave = (int)threadIdx.x >> 6, lane = (int)threadIdx.x & 63;
    for (int i = 0; i < 64; ++i) {
        int rr  = r0 + wave * 64 + i;
        int nbi = nbs[wave * 64 + i];
        const float4* xr = (const float4*)(x + (size_t)rr  * DIM);
        const float4* xn = (const float4*)(x + (size_t)nbi * DIM);
        float4 a0 = xr[lane * 2],     b0 = xn[lane * 2];
        float4 a1 = xr[lane * 2 + 1], b1 = xn[lane * 2 + 1];
        float d0 = a0.x - b0.x + 1e-6f, d1 = a0.y - b0.y + 1e-6f;
        float d2 = a0.z - b0.z + 1e-6f, d3 = a0.w - b0.w + 1e-6f;
        float d4 = a1.x - b1.x + 1e-6f, d5 = a1.y - b1.y + 1e-6f;
        float d6 = a1.z - b1.z + 1e-6f, d7 = a1.w - b1.w + 1e-6f;
        float s = d0 * d0;
        s = fmaf(d1, d1, s); s = fmaf(d2, d2, s); s = fmaf(d3, d3, s);
        s = fmaf(d4, d4, s); s = fmaf(d5, d5, s); s = fmaf(d6, d6, s);
        s = fmaf(d7, d7, s);
#pragma unroll
        for (int m = 1; m < 64; m <<= 1) s += __shfl_xor(s, m, 64);
        if (lane == 0) rowloss[rr] = logf(sqrtf(s) + 1e-8f);
    }
}

// =====================================================================
// Kernel 4: deterministic single-block reduction -> scalar
// =====================================================================
__global__ void k_reduce(const float* __restrict__ rowloss, float* __restrict__ out) {
    __shared__ float sm[256];
    float s = 0.f;
    for (int i = (int)threadIdx.x; i < N_PTS; i += 256) s += rowloss[i];
    sm[threadIdx.x] = s;
    __syncthreads();
    for (int st = 128; st > 0; st >>= 1) {
        if ((int)threadIdx.x < st) sm[threadIdx.x] += sm[threadIdx.x + st];
        __syncthreads();
    }
    if (threadIdx.x == 0) out[0] = -0.1f * sm[0] / (float)N_PTS;
}

extern "C" void kernel_launch(void* const* d_in, const int* in_sizes, int n_in,
                              void* d_out, int out_size, void* d_ws, size_t ws_size,
                              hipStream_t stream) {
    const float* x = (const float*)d_in[0];
    float* out = (float*)d_out;
    char* ws = (char*)d_ws;

    // layout: [xq 8MB][PT (64+128)*16384 u32 = 12.6MB][rowloss 64KB]
    const size_t xqB = (size_t)N_PTS * DIM;                   // 8 MB
    const size_t ptB = (size_t)(NCB + NRB) * N_PTS * 4;       // 12.58 MB
    char*     xq = ws;
    unsigned* PT = (unsigned*)(ws + xqB);
    float*    rowloss = (float*)(ws + xqB + ptB);

    k_quant<<<dim3(4096), dim3(256), 0, stream>>>(x, xq);
    k_gemm_argmax<<<dim3(NTILE), dim3(512), 0, stream>>>(xq, PT);
    k_nn<<<dim3(N_PTS / 256), dim3(256), 0, stream>>>(PT, x, rowloss);
    k_reduce<<<dim3(1), dim3(256), 0, stream>>>(rowloss, out);
}

// Round 12
// 164.278 us; speedup vs baseline: 1.1974x; 1.1974x over previous
//
#include <hip/hip_runtime.h>
#include <hip/hip_bf16.h>
#include <math.h>

#define N_PTS 16384
#define DIM   512
#define BMR   128               // tile rows
#define BNC   256               // tile cols
#define BK    64                // i8: 64-byte LDS rows
#define NRB   (N_PTS / BMR)     // 128 row-blocks
#define NCB   (N_PTS / BNC)     // 64 col-blocks
#define NTILE 4160              // sum_{g=0}^{63} 2*(64-g)
#define QSCALE 23.0f
#define BIAS   (1 << 23)        // |dot| <= 512*127^2 = 8258048 < 2^23

typedef int i32x4  __attribute__((ext_vector_type(4)));
typedef int i32x16 __attribute__((ext_vector_type(16)));
typedef unsigned long long u64;

#define VMC3    asm volatile("s_waitcnt vmcnt(3)" ::: "memory")
#define VMC0    asm volatile("s_waitcnt vmcnt(0)" ::: "memory")
#define BARRIER __builtin_amdgcn_s_barrier()

__device__ __forceinline__ u64 pmax64(u64 a, u64 b) { return a > b ? a : b; }
__device__ __forceinline__ unsigned umax32(unsigned a, unsigned b) { return a > b ? a : b; }
// DPP-based max step (VALU, off the LDS crossbar). CTRL must be literal.
template <int CTRL>
__device__ __forceinline__ unsigned dppmax(unsigned p) {
    int t = __builtin_amdgcn_update_dpp(0, (int)p, CTRL, 0xF, 0xF, true);
    return umax32(p, (unsigned)t);
}
__device__ __forceinline__ void gll(const char* g, char* l) {
    __builtin_amdgcn_global_load_lds(
        (const __attribute__((address_space(1))) void*)g,
        (__attribute__((address_space(3))) void*)l, 16, 0, 0);
}

// =====================================================================
// Kernel 1: fp32 -> int8 quantize
// =====================================================================
__global__ void k_quant(const float* __restrict__ x, char* __restrict__ xq) {
    int t = blockIdx.x * blockDim.x + threadIdx.x;
    size_t e = (size_t)t * 8;
    float4 f0 = *(const float4*)(x + e);
    float4 f1 = *(const float4*)(x + e + 4);
    auto q8 = [](float v) -> int {
        return (int)rintf(fminf(fmaxf(v * QSCALE, -127.0f), 127.0f));
    };
    int lo = (q8(f0.x) & 255) | ((q8(f0.y) & 255) << 8)
           | ((q8(f0.z) & 255) << 16) | ((q8(f0.w) & 255) << 24);
    int hi = (q8(f1.x) & 255) | ((q8(f1.y) & 255) << 8)
           | ((q8(f1.z) & 255) << 16) | ((q8(f1.w) & 255) << 24);
    int2 o; o.x = lo; o.y = hi;
    *(int2*)(xq + e) = o;
}

// =====================================================================
// Kernel 2 (byte-identical to R10-verified): 128x256 tiles, 8 waves 2x4,
// wave tile 64x64, i8 MFMA, BK=64, triple-buffer counted vmcnt(3),
// XOR-swizzled LDS, swizzle-free DPP epilogue -> PT slots.
// =====================================================================
__global__ __launch_bounds__(512, 4)
void k_gemm_argmax(const char* __restrict__ xq, unsigned* __restrict__ PT) {
    __shared__ __align__(16) char As0[BMR * BK], As1[BMR * BK], As2[BMR * BK];   // 8 KB ea
    __shared__ __align__(16) char Bs0[BNC * BK], Bs1[BNC * BK], Bs2[BNC * BK];   // 16 KB ea

    // T1: XCD swizzle (4160 % 8 == 0)
    int t0i = (int)blockIdx.x;
    int t = (t0i & 7) * (NTILE / 8) + (t0i >> 3);

    // decode t -> (br, bc): groups g = br>>1, S(g) = g*(129-g)
    int g = (int)((129.0f - sqrtf(16641.0f - 4.0f * (float)t)) * 0.5f);
    while (g * (129 - g) > t) --g;
    while ((g + 1) * (128 - g) <= t) ++g;
    int u = t - g * (129 - g);
    int bc = g + (u >> 1);
    int br = 2 * g + (u & 1);

    const int tid  = (int)threadIdx.x;
    const int lane = tid & 63;
    const int wave = tid >> 6;       // 0..7
    const int wr   = wave >> 2;      // 0/1 -> 64-row band
    const int wc   = wave & 3;       // 0..3 -> 64-col band
    const int l31  = lane & 31;
    const int h    = lane >> 5;

    const int arow0 = br * BMR;
    const int bcol0 = bc * BNC;

    // staging: A = 512 chunks (1/thread), B = 1024 chunks (2/thread)
    // LDS linear; SOURCE inverse-swizzled: col16 = (tid&3) ^ ((row>>1)&3)
    const int srow   = tid >> 2;                        // 0..127
    const int scol16 = (tid & 3) ^ ((tid >> 3) & 3);
    const char* gA  = xq + (size_t)(arow0 + srow)       * DIM + scol16 * 16;
    const char* gB0 = xq + (size_t)(bcol0 + srow)       * DIM + scol16 * 16;
    const char* gB1 = xq + (size_t)(bcol0 + 128 + srow) * DIM + scol16 * 16;
    const int cbA  = (tid & ~63) * 16;
    const int cbB0 = cbA;
    const int cbB1 = (512 + (tid & ~63)) * 16;

#define STAGE(Ad, Bd, kt)                                                \
    do {                                                                 \
        int ko = (kt) * BK;                                              \
        gll(gA + ko, (Ad) + cbA);                                        \
        gll(gB0 + ko, (Bd) + cbB0);                                      \
        gll(gB1 + ko, (Bd) + cbB1);                                      \
    } while (0)

    // fragment read byte offsets: row*64 + ((q ^ ((row>>1)&3))<<4), q=s*2+h
    const int rw = (l31 >> 1) & 3;
    const int aoff0 = (wr * 64 + 0  + l31) * 64 + ((h ^ rw) << 4);
    const int aoff1 = (wr * 64 + 32 + l31) * 64 + ((h ^ rw) << 4);
    const int boff0 = (wc * 64 + 0  + l31) * 64 + ((h ^ rw) << 4);
    const int boff1 = (wc * 64 + 32 + l31) * 64 + ((h ^ rw) << 4);

    i32x16 acc[2][2] = {};

#define COMPUTE(As_, Bs_)                                                              \
    do {                                                                               \
        _Pragma("unroll")                                                              \
        for (int s = 0; s < 2; ++s) {                                                  \
            const int xo = s * 32;                                                     \
            i32x4 a0 = *(const i32x4*)((As_) + (aoff0 ^ xo));                          \
            i32x4 a1 = *(const i32x4*)((As_) + (aoff1 ^ xo));                          \
            i32x4 b0 = *(const i32x4*)((Bs_) + (boff0 ^ xo));                          \
            i32x4 b1 = *(const i32x4*)((Bs_) + (boff1 ^ xo));                          \
            acc[0][0] = __builtin_amdgcn_mfma_i32_32x32x32_i8(a0, b0, acc[0][0], 0, 0, 0); \
            acc[0][1] = __builtin_amdgcn_mfma_i32_32x32x32_i8(a0, b1, acc[0][1], 0, 0, 0); \
            acc[1][0] = __builtin_amdgcn_mfma_i32_32x32x32_i8(a1, b0, acc[1][0], 0, 0, 0); \
            acc[1][1] = __builtin_amdgcn_mfma_i32_32x32x32_i8(a1, b1, acc[1][1], 0, 0, 0); \
        }                                                                              \
    } while (0)

    // ---- prologue: stage tiles 0,1; wait tile 0 only ----
    STAGE(As0, Bs0, 0);
    STAGE(As1, Bs1, 1);
    VMC3;
    BARRIER;

    // ---- 8 K-tiles, buffers rotate 0,1,2; vmcnt(3) counted, never 0 mid-loop ----
    STAGE(As2, Bs2, 2); COMPUTE(As0, Bs0); VMC3; BARRIER;
    STAGE(As0, Bs0, 3); COMPUTE(As1, Bs1); VMC3; BARRIER;
    STAGE(As1, Bs1, 4); COMPUTE(As2, Bs2); VMC3; BARRIER;
    STAGE(As2, Bs2, 5); COMPUTE(As0, Bs0); VMC3; BARRIER;
    STAGE(As0, Bs0, 6); COMPUTE(As1, Bs1); VMC3; BARRIER;
    STAGE(As1, Bs1, 7); COMPUTE(As2, Bs2); VMC3; BARRIER;
    COMPUTE(As0, Bs0);  VMC0; BARRIER;          // after this barrier As0/Bs0 quiesced
    COMPUTE(As1, Bs1);                          // t7

    // ---- epilogue (swizzle-free) ----
    // C/D 32x32 layout: col = lane&31, row = (r&3) + 8*(r>>2) + 4*(lane>>5)
    const bool diag = ((br >> 1) == bc);
    const int  poff = (br & 1) * 128;
    unsigned* rbuf = (unsigned*)As0;   // [128][8] row partials (4 KB)
    unsigned* cbuf = (unsigned*)Bs0;   // [256][4] col partials (4 KB)
    const int cl0 = wc * 64 + l31;
    const int s16 = (l31 >> 4) & 1;
    const unsigned Cr0 = ((unsigned)BIAS << 8) | (unsigned)(255 - cl0);
    const unsigned Cr1 = Cr0 - 32;

    auto epi = [&](bool dg) {
#pragma unroll
        for (int m = 0; m < 2; ++m) {
#pragma unroll
            for (int r = 0; r < 16; ++r) {
                int rl = wr * 64 + m * 32 + (r & 3) + 8 * (r >> 2) + 4 * h;
                unsigned q0 = ((unsigned)acc[m][0][r] << 8) + Cr0;
                unsigned q1 = ((unsigned)acc[m][1][r] << 8) + Cr1;
                if (dg && cl0 == rl + poff) q0 = 0;
                if (dg && cl0 + 32 == rl + poff) q1 = 0;
                unsigned p = umax32(q0, q1);
                p = dppmax<0xB1>(p);    // xor1
                p = dppmax<0x4E>(p);    // xor2
                p = dppmax<0x141>(p);   // half_mirror
                p = dppmax<0x140>(p);   // mirror
                if ((l31 & 15) == 0) rbuf[rl * 8 + wc * 2 + s16] = p;
            }
        }
#pragma unroll
        for (int n = 0; n < 2; ++n) {
            int cl = cl0 + n * 32;
            unsigned bst = 0;
#pragma unroll
            for (int m = 0; m < 2; ++m) {
#pragma unroll
                for (int r = 0; r < 16; ++r) {
                    int base = wr * 64 + m * 32 + (r & 3) + 8 * (r >> 2);
                    unsigned q = ((unsigned)acc[m][n][r] << 7)
                               + (((unsigned)BIAS << 7) | (unsigned)(127 - base));
                    if (dg && cl == base + 4 * h + poff) q = 0;
                    bst = umax32(bst, q);
                }
            }
            bst -= (unsigned)(4 * h);
            cbuf[cl * 4 + wr * 2 + h] = bst;
        }
    };
    if (diag) epi(true); else epi(false);

    __syncthreads();
    if (tid < 128) {
        const unsigned* rb = rbuf + tid * 8;
        unsigned w = umax32(umax32(umax32(rb[0], rb[1]), umax32(rb[2], rb[3])),
                            umax32(umax32(rb[4], rb[5]), umax32(rb[6], rb[7])));
        PT[(size_t)bc * N_PTS + arow0 + tid] = w;               // row-view slot bc
    } else if (tid < 384) {
        int c = tid - 128;
        const unsigned* cb = cbuf + c * 4;
        unsigned w = umax32(umax32(cb[0], cb[1]), umax32(cb[2], cb[3]));
        PT[(size_t)(NCB + br) * N_PTS + bcol0 + c] = w;         // col-view slot br
    }
#undef STAGE
#undef COMPUTE
}

// =====================================================================
// Kernel 3: reduce PT -> nb[row], scanning only slots written by
// construction (row-slots bc >= r>>8, col-slots br <= 2*(r>>8)+1).
// 256 blocks x 64 threads: 4x the CU coverage of R10's 64-block launch,
// same coalescing (thread r reads PT[s*N+r], 64 consecutive u32/wave).
// =====================================================================
__global__ __launch_bounds__(64)
void k_reduceP(const unsigned* __restrict__ PT, int* __restrict__ nb) {
    int r = (int)blockIdx.x * 64 + (int)threadIdx.x;
    int rb8 = r >> 8;
    u64 bst = 0;
    for (int bc = rb8; bc < NCB; ++bc) {
        unsigned p = PT[(size_t)bc * N_PTS + r];
        unsigned j = bc * 256 + 255 - (p & 255);
        bst = pmax64(bst, ((u64)(p >> 8) << 14) | (16383 - j));
    }
    int brmax = 2 * rb8 + 1;
    for (int br = 0; br <= brmax; ++br) {
        unsigned p = PT[(size_t)(NCB + br) * N_PTS + r];
        unsigned j = br * 128 + 127 - (p & 127);
        bst = pmax64(bst, ((u64)(p >> 7) << 14) | (16383 - j));
    }
    nb[r] = 16383 - (int)(bst & 16383);
}

// =====================================================================
// Kernel 4: per-row fp32 loss term: log(||x_r - x_I + 1e-6|| + 1e-8)
// =====================================================================
__global__ void k_rowloss(const float* __restrict__ x,
                          const int* __restrict__ nb,
                          float* __restrict__ rowloss) {
    int wave = (int)threadIdx.x >> 6, lane = (int)threadIdx.x & 63;
    int r = (int)blockIdx.x * 4 + wave;
    int nbi = nb[r];
    const float4* xr = (const float4*)(x + (size_t)r   * DIM);
    const float4* xn = (const float4*)(x + (size_t)nbi * DIM);
    float s = 0.f;
#pragma unroll
    for (int i = 0; i < 2; ++i) {
        float4 a = xr[lane * 2 + i];
        float4 b = xn[lane * 2 + i];
        float d0 = a.x - b.x + 1e-6f;
        float d1 = a.y - b.y + 1e-6f;
        float d2 = a.z - b.z + 1e-6f;
        float d3 = a.w - b.w + 1e-6f;
        s = fmaf(d0, d0, s); s = fmaf(d1, d1, s);
        s = fmaf(d2, d2, s); s = fmaf(d3, d3, s);
    }
#pragma unroll
    for (int m = 1; m < 64; m <<= 1) s += __shfl_xor(s, m, 64);
    if (lane == 0) rowloss[r] = logf(sqrtf(s) + 1e-8f);
}

// =====================================================================
// Kernel 5: deterministic single-block reduction -> scalar
// =====================================================================
__global__ void k_reduce(const float* __restrict__ rowloss, float* __restrict__ out) {
    __shared__ float sm[256];
    float s = 0.f;
    for (int i = (int)threadIdx.x; i < N_PTS; i += 256) s += rowloss[i];
    sm[threadIdx.x] = s;
    __syncthreads();
    for (int st = 128; st > 0; st >>= 1) {
        if ((int)threadIdx.x < st) sm[threadIdx.x] += sm[threadIdx.x + st];
        __syncthreads();
    }
    if (threadIdx.x == 0) out[0] = -0.1f * sm[0] / (float)N_PTS;
}

extern "C" void kernel_launch(void* const* d_in, const int* in_sizes, int n_in,
                              void* d_out, int out_size, void* d_ws, size_t ws_size,
                              hipStream_t stream) {
    const float* x = (const float*)d_in[0];
    float* out = (float*)d_out;
    char* ws = (char*)d_ws;

    // layout: [xq 8MB][PT (64+128)*16384 u32 = 12.6MB][nb 64KB][rowloss 64KB]
    const size_t xqB = (size_t)N_PTS * DIM;                   // 8 MB
    const size_t ptB = (size_t)(NCB + NRB) * N_PTS * 4;       // 12.58 MB
    char*     xq = ws;
    unsigned* PT = (unsigned*)(ws + xqB);
    int*      nb = (int*)(ws + xqB + ptB);
    float*    rowloss = (float*)(ws + xqB + ptB + (size_t)N_PTS * 4);

    k_quant<<<dim3(4096), dim3(256), 0, stream>>>(x, xq);
    k_gemm_argmax<<<dim3(NTILE), dim3(512), 0, stream>>>(xq, PT);
    k_reduceP<<<dim3(N_PTS / 64), dim3(64), 0, stream>>>(PT, nb);
    k_rowloss<<<dim3(N_PTS / 4), dim3(256), 0, stream>>>(x, nb, rowloss);
    k_reduce<<<dim3(1), dim3(256), 0, stream>>>(rowloss, out);
}

// Round 13
// 119.805 us; speedup vs baseline: 1.6419x; 1.3712x over previous
//
#include <hip/hip_runtime.h>
#include <hip/hip_bf16.h>
#include <math.h>

#define N_PTS 16384
#define DIM   512
#define BMR   128               // tile rows
#define BNC   256               // tile cols
#define BK    64                // i8: 64-byte LDS rows
#define NRB   (N_PTS / BMR)     // 128 row-blocks
#define NCB   (N_PTS / BNC)     // 64 col-blocks
#define NTILE 4160              // sum_{g=0}^{63} 2*(64-g)
#define QSCALE 23.0f
#define BIAS   (1 << 23)        // |dot| <= 512*127^2 = 8258048 < 2^23

typedef int i32x4  __attribute__((ext_vector_type(4)));
typedef int i32x16 __attribute__((ext_vector_type(16)));
typedef unsigned long long u64;

#define VMC3    asm volatile("s_waitcnt vmcnt(3)" ::: "memory")
#define VMC0    asm volatile("s_waitcnt vmcnt(0)" ::: "memory")
#define BARRIER __builtin_amdgcn_s_barrier()

__device__ __forceinline__ u64 pmax64(u64 a, u64 b) { return a > b ? a : b; }
__device__ __forceinline__ unsigned umax32(unsigned a, unsigned b) { return a > b ? a : b; }
// DPP-based max step (VALU, off the LDS crossbar). CTRL must be literal.
template <int CTRL>
__device__ __forceinline__ unsigned dppmax(unsigned p) {
    int t = __builtin_amdgcn_update_dpp(0, (int)p, CTRL, 0xF, 0xF, true);
    return umax32(p, (unsigned)t);
}
__device__ __forceinline__ void gll(const char* g, char* l) {
    __builtin_amdgcn_global_load_lds(
        (const __attribute__((address_space(1))) void*)g,
        (__attribute__((address_space(3))) void*)l, 16, 0, 0);
}

// =====================================================================
// Kernel 1: fp32 -> int8 quantize
// =====================================================================
__global__ void k_quant(const float* __restrict__ x, char* __restrict__ xq) {
    int t = blockIdx.x * blockDim.x + threadIdx.x;
    size_t e = (size_t)t * 8;
    float4 f0 = *(const float4*)(x + e);
    float4 f1 = *(const float4*)(x + e + 4);
    auto q8 = [](float v) -> int {
        return (int)rintf(fminf(fmaxf(v * QSCALE, -127.0f), 127.0f));
    };
    int lo = (q8(f0.x) & 255) | ((q8(f0.y) & 255) << 8)
           | ((q8(f0.z) & 255) << 16) | ((q8(f0.w) & 255) << 24);
    int hi = (q8(f1.x) & 255) | ((q8(f1.y) & 255) << 8)
           | ((q8(f1.z) & 255) << 16) | ((q8(f1.w) & 255) << 24);
    int2 o; o.x = lo; o.y = hi;
    *(int2*)(xq + e) = o;
}

// =====================================================================
// Kernel 2 (byte-identical to R10/R12-verified): 128x256 tiles, 8 waves
// 2x4, wave tile 64x64, i8 MFMA, BK=64, triple-buffer counted vmcnt(3),
// XOR-swizzled LDS, swizzle-free DPP epilogue -> PT slots.
// =====================================================================
__global__ __launch_bounds__(512, 4)
void k_gemm_argmax(const char* __restrict__ xq, unsigned* __restrict__ PT) {
    __shared__ __align__(16) char As0[BMR * BK], As1[BMR * BK], As2[BMR * BK];   // 8 KB ea
    __shared__ __align__(16) char Bs0[BNC * BK], Bs1[BNC * BK], Bs2[BNC * BK];   // 16 KB ea

    // T1: XCD swizzle (4160 % 8 == 0)
    int t0i = (int)blockIdx.x;
    int t = (t0i & 7) * (NTILE / 8) + (t0i >> 3);

    // decode t -> (br, bc): groups g = br>>1, S(g) = g*(129-g)
    int g = (int)((129.0f - sqrtf(16641.0f - 4.0f * (float)t)) * 0.5f);
    while (g * (129 - g) > t) --g;
    while ((g + 1) * (128 - g) <= t) ++g;
    int u = t - g * (129 - g);
    int bc = g + (u >> 1);
    int br = 2 * g + (u & 1);

    const int tid  = (int)threadIdx.x;
    const int lane = tid & 63;
    const int wave = tid >> 6;       // 0..7
    const int wr   = wave >> 2;      // 0/1 -> 64-row band
    const int wc   = wave & 3;       // 0..3 -> 64-col band
    const int l31  = lane & 31;
    const int h    = lane >> 5;

    const int arow0 = br * BMR;
    const int bcol0 = bc * BNC;

    // staging: A = 512 chunks (1/thread), B = 1024 chunks (2/thread)
    // LDS linear; SOURCE inverse-swizzled: col16 = (tid&3) ^ ((row>>1)&3)
    const int srow   = tid >> 2;                        // 0..127
    const int scol16 = (tid & 3) ^ ((tid >> 3) & 3);
    const char* gA  = xq + (size_t)(arow0 + srow)       * DIM + scol16 * 16;
    const char* gB0 = xq + (size_t)(bcol0 + srow)       * DIM + scol16 * 16;
    const char* gB1 = xq + (size_t)(bcol0 + 128 + srow) * DIM + scol16 * 16;
    const int cbA  = (tid & ~63) * 16;
    const int cbB0 = cbA;
    const int cbB1 = (512 + (tid & ~63)) * 16;

#define STAGE(Ad, Bd, kt)                                                \
    do {                                                                 \
        int ko = (kt) * BK;                                              \
        gll(gA + ko, (Ad) + cbA);                                        \
        gll(gB0 + ko, (Bd) + cbB0);                                      \
        gll(gB1 + ko, (Bd) + cbB1);                                      \
    } while (0)

    // fragment read byte offsets: row*64 + ((q ^ ((row>>1)&3))<<4), q=s*2+h
    const int rw = (l31 >> 1) & 3;
    const int aoff0 = (wr * 64 + 0  + l31) * 64 + ((h ^ rw) << 4);
    const int aoff1 = (wr * 64 + 32 + l31) * 64 + ((h ^ rw) << 4);
    const int boff0 = (wc * 64 + 0  + l31) * 64 + ((h ^ rw) << 4);
    const int boff1 = (wc * 64 + 32 + l31) * 64 + ((h ^ rw) << 4);

    i32x16 acc[2][2] = {};

#define COMPUTE(As_, Bs_)                                                              \
    do {                                                                               \
        _Pragma("unroll")                                                              \
        for (int s = 0; s < 2; ++s) {                                                  \
            const int xo = s * 32;                                                     \
            i32x4 a0 = *(const i32x4*)((As_) + (aoff0 ^ xo));                          \
            i32x4 a1 = *(const i32x4*)((As_) + (aoff1 ^ xo));                          \
            i32x4 b0 = *(const i32x4*)((Bs_) + (boff0 ^ xo));                          \
            i32x4 b1 = *(const i32x4*)((Bs_) + (boff1 ^ xo));                          \
            acc[0][0] = __builtin_amdgcn_mfma_i32_32x32x32_i8(a0, b0, acc[0][0], 0, 0, 0); \
            acc[0][1] = __builtin_amdgcn_mfma_i32_32x32x32_i8(a0, b1, acc[0][1], 0, 0, 0); \
            acc[1][0] = __builtin_amdgcn_mfma_i32_32x32x32_i8(a1, b0, acc[1][0], 0, 0, 0); \
            acc[1][1] = __builtin_amdgcn_mfma_i32_32x32x32_i8(a1, b1, acc[1][1], 0, 0, 0); \
        }                                                                              \
    } while (0)

    // ---- prologue: stage tiles 0,1; wait tile 0 only ----
    STAGE(As0, Bs0, 0);
    STAGE(As1, Bs1, 1);
    VMC3;
    BARRIER;

    // ---- 8 K-tiles, buffers rotate 0,1,2; vmcnt(3) counted, never 0 mid-loop ----
    STAGE(As2, Bs2, 2); COMPUTE(As0, Bs0); VMC3; BARRIER;
    STAGE(As0, Bs0, 3); COMPUTE(As1, Bs1); VMC3; BARRIER;
    STAGE(As1, Bs1, 4); COMPUTE(As2, Bs2); VMC3; BARRIER;
    STAGE(As2, Bs2, 5); COMPUTE(As0, Bs0); VMC3; BARRIER;
    STAGE(As0, Bs0, 6); COMPUTE(As1, Bs1); VMC3; BARRIER;
    STAGE(As1, Bs1, 7); COMPUTE(As2, Bs2); VMC3; BARRIER;
    COMPUTE(As0, Bs0);  VMC0; BARRIER;          // after this barrier As0/Bs0 quiesced
    COMPUTE(As1, Bs1);                          // t7

    // ---- epilogue (swizzle-free) ----
    // C/D 32x32 layout: col = lane&31, row = (r&3) + 8*(r>>2) + 4*(lane>>5)
    const bool diag = ((br >> 1) == bc);
    const int  poff = (br & 1) * 128;
    unsigned* rbuf = (unsigned*)As0;   // [128][8] row partials (4 KB)
    unsigned* cbuf = (unsigned*)Bs0;   // [256][4] col partials (4 KB)
    const int cl0 = wc * 64 + l31;
    const int s16 = (l31 >> 4) & 1;
    const unsigned Cr0 = ((unsigned)BIAS << 8) | (unsigned)(255 - cl0);
    const unsigned Cr1 = Cr0 - 32;

    auto epi = [&](bool dg) {
#pragma unroll
        for (int m = 0; m < 2; ++m) {
#pragma unroll
            for (int r = 0; r < 16; ++r) {
                int rl = wr * 64 + m * 32 + (r & 3) + 8 * (r >> 2) + 4 * h;
                unsigned q0 = ((unsigned)acc[m][0][r] << 8) + Cr0;
                unsigned q1 = ((unsigned)acc[m][1][r] << 8) + Cr1;
                if (dg && cl0 == rl + poff) q0 = 0;
                if (dg && cl0 + 32 == rl + poff) q1 = 0;
                unsigned p = umax32(q0, q1);
                p = dppmax<0xB1>(p);    // xor1
                p = dppmax<0x4E>(p);    // xor2
                p = dppmax<0x141>(p);   // half_mirror
                p = dppmax<0x140>(p);   // mirror
                if ((l31 & 15) == 0) rbuf[rl * 8 + wc * 2 + s16] = p;
            }
        }
#pragma unroll
        for (int n = 0; n < 2; ++n) {
            int cl = cl0 + n * 32;
            unsigned bst = 0;
#pragma unroll
            for (int m = 0; m < 2; ++m) {
#pragma unroll
                for (int r = 0; r < 16; ++r) {
                    int base = wr * 64 + m * 32 + (r & 3) + 8 * (r >> 2);
                    unsigned q = ((unsigned)acc[m][n][r] << 7)
                               + (((unsigned)BIAS << 7) | (unsigned)(127 - base));
                    if (dg && cl == base + 4 * h + poff) q = 0;
                    bst = umax32(bst, q);
                }
            }
            bst -= (unsigned)(4 * h);
            cbuf[cl * 4 + wr * 2 + h] = bst;
        }
    };
    if (diag) epi(true); else epi(false);

    __syncthreads();
    if (tid < 128) {
        const unsigned* rb = rbuf + tid * 8;
        unsigned w = umax32(umax32(umax32(rb[0], rb[1]), umax32(rb[2], rb[3])),
                            umax32(umax32(rb[4], rb[5]), umax32(rb[6], rb[7])));
        PT[(size_t)bc * N_PTS + arow0 + tid] = w;               // row-view slot bc
    } else if (tid < 384) {
        int c = tid - 128;
        const unsigned* cb = cbuf + c * 4;
        unsigned w = umax32(umax32(cb[0], cb[1]), umax32(cb[2], cb[3]));
        PT[(size_t)(NCB + br) * N_PTS + bcol0 + c] = w;         // col-view slot br
    }
#undef STAGE
#undef COMPUTE
}

// =====================================================================
// Kernel 3 (fused, full-chip): 1024 blocks x 256 threads, 16 rows/block.
// Phase 1: 16 threads per row cooperatively scan the row's live PT slots
// (<=12 independent loads/thread -> MLP, no serial 96-load chain),
// 16-lane shfl_xor reduce on packed (value,~j), nb -> LDS.
// Phase 2: 4 waves x 4 rows: fp32 distance + log -> rowloss.
// =====================================================================
__global__ __launch_bounds__(256)
void k_nnloss(const unsigned* __restrict__ PT, const float* __restrict__ x,
              float* __restrict__ rowloss) {
    __shared__ int nbs[16];
    const int tid = (int)threadIdx.x;
    const int r0  = (int)blockIdx.x * 16;

    // ---- phase 1: cooperative slot scan ----
    {
        const int gi = tid >> 4;        // group -> row r0+gi
        const int ti = tid & 15;
        const int r  = r0 + gi;
        const int rb8 = r >> 8;         // uniform across block (16 | 256)
        u64 bst = 0;
        for (int bc = rb8 + ti; bc < NCB; bc += 16) {
            unsigned p = PT[(size_t)bc * N_PTS + r];
            unsigned j = bc * 256 + 255 - (p & 255);
            bst = pmax64(bst, ((u64)(p >> 8) << 14) | (16383 - j));
        }
        const int brmax = 2 * rb8 + 1;
        for (int br = ti; br <= brmax; br += 16) {
            unsigned p = PT[(size_t)(NCB + br) * N_PTS + r];
            unsigned j = br * 128 + 127 - (p & 127);
            bst = pmax64(bst, ((u64)(p >> 7) << 14) | (16383 - j));
        }
#pragma unroll
        for (int m = 1; m < 16; m <<= 1)
            bst = pmax64(bst, (u64)__shfl_xor((unsigned long long)bst, m, 64));
        if (ti == 0) nbs[gi] = 16383 - (int)(bst & 16383);
    }
    __syncthreads();

    // ---- phase 2: distance + log (4 waves x 4 rows) ----
    const int wv = tid >> 6, lane = tid & 63;
    for (int i = 0; i < 4; ++i) {
        int rl  = wv * 4 + i;
        int rr  = r0 + rl;
        int nbi = nbs[rl];
        const float4* xr = (const float4*)(x + (size_t)rr  * DIM);
        const float4* xn = (const float4*)(x + (size_t)nbi * DIM);
        float4 a0 = xr[lane * 2],     b0 = xn[lane * 2];
        float4 a1 = xr[lane * 2 + 1], b1 = xn[lane * 2 + 1];
        float d0 = a0.x - b0.x + 1e-6f, d1 = a0.y - b0.y + 1e-6f;
        float d2 = a0.z - b0.z + 1e-6f, d3 = a0.w - b0.w + 1e-6f;
        float d4 = a1.x - b1.x + 1e-6f, d5 = a1.y - b1.y + 1e-6f;
        float d6 = a1.z - b1.z + 1e-6f, d7 = a1.w - b1.w + 1e-6f;
        float s = d0 * d0;
        s = fmaf(d1, d1, s); s = fmaf(d2, d2, s); s = fmaf(d3, d3, s);
        s = fmaf(d4, d4, s); s = fmaf(d5, d5, s); s = fmaf(d6, d6, s);
        s = fmaf(d7, d7, s);
#pragma unroll
        for (int m = 1; m < 64; m <<= 1) s += __shfl_xor(s, m, 64);
        if (lane == 0) rowloss[rr] = logf(sqrtf(s) + 1e-8f);
    }
}

// =====================================================================
// Kernel 4: deterministic single-block reduction -> scalar (float4 loads)
// =====================================================================
__global__ void k_reduce(const float* __restrict__ rowloss, float* __restrict__ out) {
    __shared__ float sm[256];
    const float4* rl4 = (const float4*)rowloss;
    float s = 0.f;
#pragma unroll
    for (int i = 0; i < 16; ++i) {
        float4 v = rl4[i * 256 + threadIdx.x];
        s += (v.x + v.y) + (v.z + v.w);
    }
    sm[threadIdx.x] = s;
    __syncthreads();
    for (int st = 128; st > 0; st >>= 1) {
        if ((int)threadIdx.x < st) sm[threadIdx.x] += sm[threadIdx.x + st];
        __syncthreads();
    }
    if (threadIdx.x == 0) out[0] = -0.1f * sm[0] / (float)N_PTS;
}

extern "C" void kernel_launch(void* const* d_in, const int* in_sizes, int n_in,
                              void* d_out, int out_size, void* d_ws, size_t ws_size,
                              hipStream_t stream) {
    const float* x = (const float*)d_in[0];
    float* out = (float*)d_out;
    char* ws = (char*)d_ws;

    // layout: [xq 8MB][PT (64+128)*16384 u32 = 12.6MB][rowloss 64KB]
    const size_t xqB = (size_t)N_PTS * DIM;                   // 8 MB
    const size_t ptB = (size_t)(NCB + NRB) * N_PTS * 4;       // 12.58 MB
    char*     xq = ws;
    unsigned* PT = (unsigned*)(ws + xqB);
    float*    rowloss = (float*)(ws + xqB + ptB);

    k_quant<<<dim3(4096), dim3(256), 0, stream>>>(x, xq);
    k_gemm_argmax<<<dim3(NTILE), dim3(512), 0, stream>>>(xq, PT);
    k_nnloss<<<dim3(N_PTS / 16), dim3(256), 0, stream>>>(PT, x, rowloss);
    k_reduce<<<dim3(1), dim3(256), 0, stream>>>(rowloss, out);
}